// Round 3
// baseline (945.811 us; speedup 1.0000x reference)
//
#include <hip/hip_runtime.h>
#include <hip/hip_cooperative_groups.h>
#include <math.h>

namespace cg = cooperative_groups;

#define FL 48
#define NBLK 512
#define NTHR 256
#define TTOT (NBLK * NTHR)

struct Params {
  const float* ximg;
  const int *e0, *e1, *e2, *e3;
  const float *g1Wl, *g1bl, *g1Wr;
  const float *gWl[3], *gbl[3], *gWr[3];
  const float *amW[3], *amb[3], *axW[3], *axb[3];
  const float *cWl[3], *cbl[3], *cWr[3];
  const float *fc1W, *fc1b, *fc2W, *fc2b;
  float* out;
  float *xp1, *xp2, *xp3, *x4, *dr;
  float *cnt0, *cnt1, *cnt2, *cnt3;
  float *aggS0, *aggS1, *aggS2, *aggS3;
  float *aggC2, *aggC3, *aggC4;
  float *sum1, *max1, *sum2, *max2, *sum3, *max3;
  float *fc1acc;
  float *zbase;
  int zcount;
};

__device__ __forceinline__ float sigmoidf(float v) { return 1.0f / (1.0f + expf(-v)); }

// att[t] = sigmoid(mean@amW + amb + max@axW + axb), computed redundantly per block into LDS
__device__ void compute_att_lds(const float* sum, const float* mxv, float invN,
                                const float* amW, const float* amb,
                                const float* axW, const float* axb, float* sAtt) {
  int t = threadIdx.x;
  if (t < FL) {
    float s = amb[t] + axb[t];
    for (int ci = 0; ci < FL; ++ci)
      s += (sum[ci] * invN) * amW[ci * FL + t] + mxv[ci] * axW[ci * FL + t];
    sAtt[t] = sigmoidf(s);
  }
  // grid.sync()/syncthreads follows before any use
}

template <int POOL>
__device__ void do_level(cg::grid_group& grid, int gid,
                         const float* x, int N, int H, const int* e, int E,
                         const float* cnt,
                         const float* cWl, const float* cbl, const float* cWr,
                         const float* amW, const float* amb,
                         const float* axW, const float* axb,
                         const float* Wl, const float* bl, const float* Wr,
                         const float* sum, const float* mxv,
                         float* dr, float* aggS, float* aggC,
                         float* y, int Nout, float* nsum, float* nmax,
                         float* sWl, float* sWr, float* sAtt) {
  // Phase A: per-node dr = x.cWr ; per-edge dot-scatter aggS[d] += x[s].cWl
  for (int i = gid; i < N + E; i += TTOT) {
    if (i < N) {
      float b = 0.0f;
      const float* xr = x + i * FL;
      for (int c = 0; c < FL; ++c) b += xr[c] * cWr[c];
      dr[i] = b;
    } else {
      int ei = i - N;
      int s = e[ei];
      float a = 0.0f;
      const float* xr = x + s * FL;
      for (int c = 0; c < FL; ++c) a += xr[c] * cWl[c];
      atomicAdd(&aggS[e[E + ei]], a);
    }
  }
  compute_att_lds(sum, mxv, 1.0f / (float)N, amW, amb, axW, axb, sAtt);
  grid.sync();

  float cb = cbl[0];
  // Phase C: gated edge scatter aggC[d][c] += x[s][c]*(1+att[c]+ch[s])
  for (int g = gid; g < E * FL; g += TTOT) {
    int ei = g / FL, c = g % FL;
    int s = e[ei], d = e[E + ei];
    float ch = sigmoidf(aggS[s] / fmaxf(cnt[s], 1.0f) + cb + dr[s]);
    atomicAdd(&aggC[d * FL + c], x[s * FL + c] * (1.0f + sAtt[c] + ch));
  }
  // stage SAGE weights for phase D (reads complete before barrier use)
  for (int i = threadIdx.x; i < FL * FL; i += NTHR) { sWl[i] = Wl[i]; sWr[i] = Wr[i]; }
  grid.sync();

  // Phase D: gated SAGE (+pool) + next-level stats
  for (int g = gid; g < Nout * FL; g += TTOT) {
    int c = g % FL, m = g / FL;
    float result;
    if (POOL) {
      int Ho = H >> 1;
      int a = m / Ho, b = m % Ho;
      float best = -INFINITY;
#pragma unroll
      for (int da = 0; da < 2; ++da)
#pragma unroll
        for (int db = 0; db < 2; ++db) {
          int n = (2 * a + da) * H + (2 * b + db);
          float rc = 1.0f / fmaxf(cnt[n], 1.0f);
          float ch = sigmoidf(aggS[n] * rc + cb + dr[n]);
          const float* xr = x + n * FL;
          const float* ar = aggC + n * FL;
          float s = bl[c];
          for (int ci = 0; ci < FL; ++ci)
            s += ar[ci] * rc * sWl[ci * FL + c] +
                 xr[ci] * (1.0f + sAtt[ci] + ch) * sWr[ci * FL + c];
          best = fmaxf(best, fmaxf(s, 0.0f));
        }
      result = best;
    } else {
      int n = m;
      float rc = 1.0f / fmaxf(cnt[n], 1.0f);
      float ch = sigmoidf(aggS[n] * rc + cb + dr[n]);
      const float* xr = x + n * FL;
      const float* ar = aggC + n * FL;
      float s = bl[c];
      for (int ci = 0; ci < FL; ++ci)
        s += ar[ci] * rc * sWl[ci * FL + c] +
             xr[ci] * (1.0f + sAtt[ci] + ch) * sWr[ci * FL + c];
      result = fmaxf(s, 0.0f);
    }
    y[g] = result;
    if (nsum) {
      atomicAdd(&nsum[c], result);
      atomicMax((unsigned int*)&nmax[c], __float_as_uint(result));  // vals >= 0
    }
  }
  grid.sync();
}

__global__ __launch_bounds__(NTHR) void net_kernel(Params p) {
  cg::grid_group grid = cg::this_grid();
  const int gid = blockIdx.x * NTHR + threadIdx.x;
  __shared__ float sWl[FL * FL], sWr[FL * FL], sAtt[FL];

  // P0: zero accumulators
  for (int i = gid; i < p.zcount; i += TTOT) p.zbase[i] = 0.0f;
  grid.sync();

  // P1: degree counts x4 + level-1 scalar scatter (87040 items < TTOT)
  {
    int g = gid;
    if (g < 65536) {
      int d = p.e0[65536 + g];
      atomicAdd(&p.cnt0[d], 1.0f);
      atomicAdd(&p.aggS0[d], p.ximg[p.e0[g]]);
    } else if (g < 81920) {
      atomicAdd(&p.cnt1[p.e1[16384 + (g - 65536)]], 1.0f);
    } else if (g < 86016) {
      atomicAdd(&p.cnt2[p.e2[4096 + (g - 81920)]], 1.0f);
    } else if (g < 87040) {
      atomicAdd(&p.cnt3[p.e3[1024 + (g - 86016)]], 1.0f);
    }
  }
  grid.sync();

  // P2: sage1 (C_in=1) + relu + pool 128->64 + level-2 stats
  for (int g = gid; g < 4096 * FL; g += TTOT) {
    int c = g % FL, m = g / FL;
    int a = m >> 6, b = m & 63;
    float wl = p.g1Wl[c], wr = p.g1Wr[c], bb = p.g1bl[c];
    float best = -INFINITY;
#pragma unroll
    for (int da = 0; da < 2; ++da)
#pragma unroll
      for (int db = 0; db < 2; ++db) {
        int n = (2 * a + da) * 128 + (2 * b + db);
        float mean = p.aggS0[n] / fmaxf(p.cnt0[n], 1.0f);
        best = fmaxf(best, fmaxf(mean * wl + bb + p.ximg[n] * wr, 0.0f));
      }
    p.xp1[g] = best;
    atomicAdd(&p.sum1[c], best);
    atomicMax((unsigned int*)&p.max1[c], __float_as_uint(best));
  }
  grid.sync();

  // levels 2..4
  do_level<1>(grid, gid, p.xp1, 4096, 64, p.e1, 16384, p.cnt1,
              p.cWl[0], p.cbl[0], p.cWr[0], p.amW[0], p.amb[0], p.axW[0], p.axb[0],
              p.gWl[0], p.gbl[0], p.gWr[0], p.sum1, p.max1,
              p.dr, p.aggS1, p.aggC2, p.xp2, 1024, p.sum2, p.max2, sWl, sWr, sAtt);
  do_level<1>(grid, gid, p.xp2, 1024, 32, p.e2, 4096, p.cnt2,
              p.cWl[1], p.cbl[1], p.cWr[1], p.amW[1], p.amb[1], p.axW[1], p.axb[1],
              p.gWl[1], p.gbl[1], p.gWr[1], p.sum2, p.max2,
              p.dr, p.aggS2, p.aggC3, p.xp3, 256, p.sum3, p.max3, sWl, sWr, sAtt);
  do_level<0>(grid, gid, p.xp3, 256, 16, p.e3, 1024, p.cnt3,
              p.cWl[2], p.cbl[2], p.cWr[2], p.amW[2], p.amb[2], p.axW[2], p.axb[2],
              p.gWl[2], p.gbl[2], p.gWr[2], p.sum3, p.max3,
              p.dr, p.aggS3, p.aggC4, p.x4, 256, (float*)nullptr, (float*)nullptr,
              sWl, sWr, sAtt);

  // FC1: block b handles k in [b*24, b*24+24); k = c*256 + n -> x4[n*48+c]
  {
    __shared__ float xin[24];
    int b = blockIdx.x, t = threadIdx.x;
    int k0 = b * 24;
    if (t < 24) {
      int k = k0 + t;
      xin[t] = p.x4[(k & 255) * FL + (k >> 8)];
    }
    __syncthreads();
    float a = 0.0f;
    for (int i = 0; i < 24; ++i) a += xin[i] * p.fc1W[(k0 + i) * 256 + t];
    atomicAdd(&p.fc1acc[t], a);
  }
  grid.sync();

  // final: fc1 bias+relu, fc2, log_softmax (block 0)
  if (blockIdx.x == 0) {
    __shared__ float av[256];
    __shared__ float logits[10];
    int t = threadIdx.x;
    av[t] = fmaxf(p.fc1acc[t] + p.fc1b[t], 0.0f);
    __syncthreads();
    if (t < 10) {
      float s = p.fc2b[t];
      for (int o = 0; o < 256; ++o) s += av[o] * p.fc2W[o * 10 + t];
      logits[t] = s;
    }
    __syncthreads();
    if (t == 0) {
      float m = logits[0];
      for (int j = 1; j < 10; ++j) m = fmaxf(m, logits[j]);
      float s = 0.0f;
      for (int j = 0; j < 10; ++j) s += expf(logits[j] - m);
      float ls = logf(s);
      for (int j = 0; j < 10; ++j) p.out[j] = logits[j] - m - ls;
    }
  }
}

// ---------------- launch ----------------

extern "C" void kernel_launch(void* const* d_in, const int* in_sizes, int n_in,
                              void* d_out, int out_size, void* d_ws, size_t ws_size,
                              hipStream_t stream) {
  Params p;
  p.ximg = (const float*)d_in[0];
  p.e0 = (const int*)d_in[1];
  p.e1 = (const int*)d_in[2];
  p.e2 = (const int*)d_in[3];
  p.e3 = (const int*)d_in[4];
  p.g1Wl = (const float*)d_in[6];
  p.g1bl = (const float*)d_in[7];
  p.g1Wr = (const float*)d_in[8];
  for (int i = 0; i < 3; ++i) {
    p.gWl[i] = (const float*)d_in[9 + i * 3];
    p.gbl[i] = (const float*)d_in[10 + i * 3];
    p.gWr[i] = (const float*)d_in[11 + i * 3];
    int base = 18 + i * 7;
    p.amW[i] = (const float*)d_in[base + 0];
    p.amb[i] = (const float*)d_in[base + 1];
    p.axW[i] = (const float*)d_in[base + 2];
    p.axb[i] = (const float*)d_in[base + 3];
    p.cWl[i] = (const float*)d_in[base + 4];
    p.cbl[i] = (const float*)d_in[base + 5];
    p.cWr[i] = (const float*)d_in[base + 6];
  }
  p.fc1W = (const float*)d_in[46];
  p.fc1b = (const float*)d_in[47];
  p.fc2W = (const float*)d_in[48];
  p.fc2b = (const float*)d_in[49];
  p.out = (float*)d_out;

  const int N0 = 16384, N1 = 4096, N2 = 1024, N3 = 256;
  float* f = (float*)d_ws;
  p.xp1 = f;                   f += N1 * FL;
  p.xp2 = f;                   f += N2 * FL;
  p.xp3 = f;                   f += N3 * FL;
  p.x4 = f;                    f += N3 * FL;
  p.dr = f;                    f += N1;
  p.zbase = f;
  p.cnt0 = f;                  f += N0;
  p.cnt1 = f;                  f += N1;
  p.cnt2 = f;                  f += N2;
  p.cnt3 = f;                  f += N3;
  p.aggS0 = f;                 f += N0;
  p.aggS1 = f;                 f += N1;
  p.aggS2 = f;                 f += N2;
  p.aggS3 = f;                 f += N3;
  p.aggC2 = f;                 f += N1 * FL;
  p.aggC3 = f;                 f += N2 * FL;
  p.aggC4 = f;                 f += N3 * FL;
  p.sum1 = f;                  f += FL;
  p.max1 = f;                  f += FL;
  p.sum2 = f;                  f += FL;
  p.max2 = f;                  f += FL;
  p.sum3 = f;                  f += FL;
  p.max3 = f;                  f += FL;
  p.fc1acc = f;                f += 256;
  p.zcount = (int)(f - p.zbase);

  void* args[] = {&p};
  hipLaunchCooperativeKernel((const void*)net_kernel, dim3(NBLK), dim3(NTHR), args, 0, stream);

  (void)in_sizes; (void)n_in; (void)out_size; (void)ws_size;
}

// Round 4
// 378.261 us; speedup vs baseline: 2.5004x; 2.5004x over previous
//
#include <hip/hip_runtime.h>
#include <hip/hip_cooperative_groups.h>
#include <math.h>

#define FL 48
#define NBLK 256
#define NTHR 256
#define TTOT (NBLK * NTHR)

struct Params {
  const float* ximg;
  const int *e0, *e1, *e2, *e3;
  const float *g1Wl, *g1bl, *g1Wr;
  const float *gWl[3], *gbl[3], *gWr[3];
  const float *amW[3], *amb[3], *axW[3], *axb[3];
  const float *cWl[3], *cbl[3], *cWr[3];
  const float *fc1W, *fc1b, *fc2W, *fc2b;
  float* out;
  unsigned* bar;
  float *xp1, *xp2, *xp3, *x4, *dr;
  float *cnt0, *cnt1, *cnt2, *cnt3;
  float *aggS0, *aggS1, *aggS2, *aggS3;
  float *aggC2, *aggC3, *aggC4;
  float *sum1, *max1, *sum2, *max2, *sum3, *max3;
  float *fc1acc;
  float *zbase;
  int zcount;
};

__device__ __forceinline__ float sigmoidf(float v) { return 1.0f / (1.0f + expf(-v)); }

// Custom grid barrier: agent-scope arrive/spin + __threadfence for cross-XCD
// data visibility (release: L2 writeback; acquire: L2 invalidate).
__device__ __forceinline__ void gbar(unsigned* bar) {
  __syncthreads();
  if (threadIdx.x == 0) {
    __threadfence();  // release this block's (XCD's) writes to coherence point
    unsigned g = __hip_atomic_load(&bar[1], __ATOMIC_RELAXED, __HIP_MEMORY_SCOPE_AGENT);
    unsigned old = __hip_atomic_fetch_add(&bar[0], 1u, __ATOMIC_RELAXED, __HIP_MEMORY_SCOPE_AGENT);
    if (old == NBLK - 1u) {
      __hip_atomic_store(&bar[0], 0u, __ATOMIC_RELAXED, __HIP_MEMORY_SCOPE_AGENT);
      __hip_atomic_store(&bar[1], g + 1u, __ATOMIC_RELEASE, __HIP_MEMORY_SCOPE_AGENT);
    } else {
      while (__hip_atomic_load(&bar[1], __ATOMIC_RELAXED, __HIP_MEMORY_SCOPE_AGENT) == g)
        __builtin_amdgcn_s_sleep(2);
    }
    __threadfence();  // acquire: drop stale lines before reading others' data
  }
  __syncthreads();
}

// att[t] = sigmoid(mean@amW + amb + max@axW + axb), redundant per block into LDS
__device__ void compute_att_lds(const float* sum, const float* mxv, float invN,
                                const float* amW, const float* amb,
                                const float* axW, const float* axb, float* sAtt) {
  int t = threadIdx.x;
  if (t < FL) {
    float s = amb[t] + axb[t];
    for (int ci = 0; ci < FL; ++ci)
      s += (sum[ci] * invN) * amW[ci * FL + t] + mxv[ci] * axW[ci * FL + t];
    sAtt[t] = sigmoidf(s);
  }
}

template <int POOL, int HAS_STATS>
__device__ void do_level(const Params& p, int gid,
                         const float* x, int N, int H, const int* e, int E,
                         const float* cnt,
                         const float* cWl, const float* cbl, const float* cWr,
                         const float* amW, const float* amb,
                         const float* axW, const float* axb,
                         const float* Wl, const float* bl, const float* Wr,
                         const float* sum, const float* mxv,
                         float* dr, float* aggS, float* aggC,
                         float* y, int Nout, float* nsum, float* nmax,
                         float* sWl, float* sWr, float* sAtt,
                         float* lsum, unsigned* lmax) {
  // Phase A: dr[i] = x[i].cWr ; per-edge dot scatter aggS[d] += x[s].cWl ; att into LDS
  for (int i = gid; i < N + E; i += TTOT) {
    if (i < N) {
      float b = 0.0f;
      const float* xr = x + i * FL;
      for (int c = 0; c < FL; ++c) b += xr[c] * cWr[c];
      dr[i] = b;
    } else {
      int ei = i - N;
      int s = e[ei];
      float a = 0.0f;
      const float* xr = x + s * FL;
      for (int c = 0; c < FL; ++c) a += xr[c] * cWl[c];
      atomicAdd(&aggS[e[E + ei]], a);
    }
  }
  compute_att_lds(sum, mxv, 1.0f / (float)N, amW, amb, axW, axb, sAtt);
  gbar(p.bar);

  float cb = cbl[0];
  // Phase C: gated edge scatter aggC[d][c] += x[s][c]*(1+att[c]+ch[s]); stage weights
  for (int g = gid; g < E * FL; g += TTOT) {
    int ei = g / FL, c = g % FL;
    int s = e[ei], d = e[E + ei];
    float ch = sigmoidf(aggS[s] / fmaxf(cnt[s], 1.0f) + cb + dr[s]);
    atomicAdd(&aggC[d * FL + c], x[s * FL + c] * (1.0f + sAtt[c] + ch));
  }
  for (int i = threadIdx.x; i < FL * FL; i += NTHR) { sWl[i] = Wl[i]; sWr[i] = Wr[i]; }
  gbar(p.bar);

  // Phase D: gated SAGE (+pool) + next-level stats via LDS partials
  if (threadIdx.x < FL) { lsum[threadIdx.x] = 0.0f; lmax[threadIdx.x] = 0u; }
  __syncthreads();
  for (int g = gid; g < Nout * FL; g += TTOT) {
    int c = g % FL, m = g / FL;
    float result;
    if (POOL) {
      int Ho = H >> 1;
      int a = m / Ho, b = m % Ho;
      float best = -INFINITY;
#pragma unroll
      for (int da = 0; da < 2; ++da)
#pragma unroll
        for (int db = 0; db < 2; ++db) {
          int n = (2 * a + da) * H + (2 * b + db);
          float rc = 1.0f / fmaxf(cnt[n], 1.0f);
          float ch = sigmoidf(aggS[n] * rc + cb + dr[n]);
          const float* xr = x + n * FL;
          const float* ar = aggC + n * FL;
          float s = bl[c];
          for (int ci = 0; ci < FL; ++ci)
            s += ar[ci] * rc * sWl[ci * FL + c] +
                 xr[ci] * (1.0f + sAtt[ci] + ch) * sWr[ci * FL + c];
          best = fmaxf(best, fmaxf(s, 0.0f));
        }
      result = best;
    } else {
      int n = m;
      float rc = 1.0f / fmaxf(cnt[n], 1.0f);
      float ch = sigmoidf(aggS[n] * rc + cb + dr[n]);
      const float* xr = x + n * FL;
      const float* ar = aggC + n * FL;
      float s = bl[c];
      for (int ci = 0; ci < FL; ++ci)
        s += ar[ci] * rc * sWl[ci * FL + c] +
             xr[ci] * (1.0f + sAtt[ci] + ch) * sWr[ci * FL + c];
      result = fmaxf(s, 0.0f);
    }
    y[g] = result;
    if (HAS_STATS) {
      atomicAdd(&lsum[c], result);
      atomicMax(&lmax[c], __float_as_uint(result));  // post-relu values >= 0
    }
  }
  __syncthreads();
  if (HAS_STATS && threadIdx.x < FL) {
    atomicAdd(&nsum[threadIdx.x], lsum[threadIdx.x]);
    atomicMax((unsigned*)&nmax[threadIdx.x], lmax[threadIdx.x]);
  }
  gbar(p.bar);
}

__global__ __launch_bounds__(NTHR) void net_kernel(Params p) {
  const int gid = blockIdx.x * NTHR + threadIdx.x;
  __shared__ float sWl[FL * FL], sWr[FL * FL], sAtt[FL];
  __shared__ float lsum[FL];
  __shared__ unsigned lmax[FL];

  // P0: zero accumulators
  for (int i = gid; i < p.zcount; i += TTOT) p.zbase[i] = 0.0f;
  gbar(p.bar);

  // P1: degree counts x4 + level-1 scalar scatter
  for (int g = gid; g < 87040; g += TTOT) {
    if (g < 65536) {
      int d = p.e0[65536 + g];
      atomicAdd(&p.cnt0[d], 1.0f);
      atomicAdd(&p.aggS0[d], p.ximg[p.e0[g]]);
    } else if (g < 81920) {
      atomicAdd(&p.cnt1[p.e1[16384 + (g - 65536)]], 1.0f);
    } else if (g < 86016) {
      atomicAdd(&p.cnt2[p.e2[4096 + (g - 81920)]], 1.0f);
    } else {
      atomicAdd(&p.cnt3[p.e3[1024 + (g - 86016)]], 1.0f);
    }
  }
  gbar(p.bar);

  // P2: sage1 (C_in=1) + relu + pool 128->64 + level-2 stats (LDS partials)
  if (threadIdx.x < FL) { lsum[threadIdx.x] = 0.0f; lmax[threadIdx.x] = 0u; }
  __syncthreads();
  for (int g = gid; g < 4096 * FL; g += TTOT) {
    int c = g % FL, m = g / FL;
    int a = m >> 6, b = m & 63;
    float wl = p.g1Wl[c], wr = p.g1Wr[c], bb = p.g1bl[c];
    float best = -INFINITY;
#pragma unroll
    for (int da = 0; da < 2; ++da)
#pragma unroll
      for (int db = 0; db < 2; ++db) {
        int n = (2 * a + da) * 128 + (2 * b + db);
        float mean = p.aggS0[n] / fmaxf(p.cnt0[n], 1.0f);
        best = fmaxf(best, fmaxf(mean * wl + bb + p.ximg[n] * wr, 0.0f));
      }
    p.xp1[g] = best;
    atomicAdd(&lsum[c], best);
    atomicMax(&lmax[c], __float_as_uint(best));
  }
  __syncthreads();
  if (threadIdx.x < FL) {
    atomicAdd(&p.sum1[threadIdx.x], lsum[threadIdx.x]);
    atomicMax((unsigned*)&p.max1[threadIdx.x], lmax[threadIdx.x]);
  }
  gbar(p.bar);

  // levels 2..4
  do_level<1, 1>(p, gid, p.xp1, 4096, 64, p.e1, 16384, p.cnt1,
                 p.cWl[0], p.cbl[0], p.cWr[0], p.amW[0], p.amb[0], p.axW[0], p.axb[0],
                 p.gWl[0], p.gbl[0], p.gWr[0], p.sum1, p.max1,
                 p.dr, p.aggS1, p.aggC2, p.xp2, 1024, p.sum2, p.max2,
                 sWl, sWr, sAtt, lsum, lmax);
  do_level<1, 1>(p, gid, p.xp2, 1024, 32, p.e2, 4096, p.cnt2,
                 p.cWl[1], p.cbl[1], p.cWr[1], p.amW[1], p.amb[1], p.axW[1], p.axb[1],
                 p.gWl[1], p.gbl[1], p.gWr[1], p.sum2, p.max2,
                 p.dr, p.aggS2, p.aggC3, p.xp3, 256, p.sum3, p.max3,
                 sWl, sWr, sAtt, lsum, lmax);
  do_level<0, 0>(p, gid, p.xp3, 256, 16, p.e3, 1024, p.cnt3,
                 p.cWl[2], p.cbl[2], p.cWr[2], p.amW[2], p.amb[2], p.axW[2], p.axb[2],
                 p.gWl[2], p.gbl[2], p.gWr[2], p.sum3, p.max3,
                 p.dr, p.aggS3, p.aggC4, p.x4, 256, (float*)nullptr, (float*)nullptr,
                 sWl, sWr, sAtt, lsum, lmax);

  // FC1: block b covers k in [b*48, b*48+48); k = c*256 + n -> x4[n*48+c]
  {
    __shared__ float xin[48];
    int k0 = blockIdx.x * 48;
    int t = threadIdx.x;
    if (t < 48) {
      int k = k0 + t;
      xin[t] = p.x4[(k & 255) * FL + (k >> 8)];
    }
    __syncthreads();
    float a = 0.0f;
    for (int i = 0; i < 48; ++i) a += xin[i] * p.fc1W[(k0 + i) * 256 + t];
    atomicAdd(&p.fc1acc[t], a);
  }
  gbar(p.bar);

  // final: fc1 bias+relu, fc2, log_softmax (block 0)
  if (blockIdx.x == 0) {
    __shared__ float av[256];
    __shared__ float logits[10];
    int t = threadIdx.x;
    av[t] = fmaxf(p.fc1acc[t] + p.fc1b[t], 0.0f);
    __syncthreads();
    if (t < 10) {
      float s = p.fc2b[t];
      for (int o = 0; o < 256; ++o) s += av[o] * p.fc2W[o * 10 + t];
      logits[t] = s;
    }
    __syncthreads();
    if (t == 0) {
      float m = logits[0];
      for (int j = 1; j < 10; ++j) m = fmaxf(m, logits[j]);
      float s = 0.0f;
      for (int j = 0; j < 10; ++j) s += expf(logits[j] - m);
      float ls = logf(s);
      for (int j = 0; j < 10; ++j) p.out[j] = logits[j] - m - ls;
    }
  }
}

// ---------------- launch ----------------

extern "C" void kernel_launch(void* const* d_in, const int* in_sizes, int n_in,
                              void* d_out, int out_size, void* d_ws, size_t ws_size,
                              hipStream_t stream) {
  Params p;
  p.ximg = (const float*)d_in[0];
  p.e0 = (const int*)d_in[1];
  p.e1 = (const int*)d_in[2];
  p.e2 = (const int*)d_in[3];
  p.e3 = (const int*)d_in[4];
  p.g1Wl = (const float*)d_in[6];
  p.g1bl = (const float*)d_in[7];
  p.g1Wr = (const float*)d_in[8];
  for (int i = 0; i < 3; ++i) {
    p.gWl[i] = (const float*)d_in[9 + i * 3];
    p.gbl[i] = (const float*)d_in[10 + i * 3];
    p.gWr[i] = (const float*)d_in[11 + i * 3];
    int base = 18 + i * 7;
    p.amW[i] = (const float*)d_in[base + 0];
    p.amb[i] = (const float*)d_in[base + 1];
    p.axW[i] = (const float*)d_in[base + 2];
    p.axb[i] = (const float*)d_in[base + 3];
    p.cWl[i] = (const float*)d_in[base + 4];
    p.cbl[i] = (const float*)d_in[base + 5];
    p.cWr[i] = (const float*)d_in[base + 6];
  }
  p.fc1W = (const float*)d_in[46];
  p.fc1b = (const float*)d_in[47];
  p.fc2W = (const float*)d_in[48];
  p.fc2b = (const float*)d_in[49];
  p.out = (float*)d_out;

  const int N0 = 16384, N1 = 4096, N2 = 1024, N3 = 256;
  p.bar = (unsigned*)d_ws;           // 128B reserved for barrier state
  float* f = (float*)d_ws + 32;
  p.xp1 = f;                   f += N1 * FL;
  p.xp2 = f;                   f += N2 * FL;
  p.xp3 = f;                   f += N3 * FL;
  p.x4 = f;                    f += N3 * FL;
  p.dr = f;                    f += N1;
  p.zbase = f;
  p.cnt0 = f;                  f += N0;
  p.cnt1 = f;                  f += N1;
  p.cnt2 = f;                  f += N2;
  p.cnt3 = f;                  f += N3;
  p.aggS0 = f;                 f += N0;
  p.aggS1 = f;                 f += N1;
  p.aggS2 = f;                 f += N2;
  p.aggS3 = f;                 f += N3;
  p.aggC2 = f;                 f += N1 * FL;
  p.aggC3 = f;                 f += N2 * FL;
  p.aggC4 = f;                 f += N3 * FL;
  p.sum1 = f;                  f += FL;
  p.max1 = f;                  f += FL;
  p.sum2 = f;                  f += FL;
  p.max2 = f;                  f += FL;
  p.sum3 = f;                  f += FL;
  p.max3 = f;                  f += FL;
  p.fc1acc = f;                f += 256;
  p.zcount = (int)(f - p.zbase);

  // reset barrier state (capture-legal async memset node)
  hipMemsetAsync(d_ws, 0, 128, stream);

  void* args[] = {&p};
  hipLaunchCooperativeKernel((const void*)net_kernel, dim3(NBLK), dim3(NTHR), args, 0, stream);

  (void)in_sizes; (void)n_in; (void)out_size; (void)ws_size;
}

// Round 5
// 349.233 us; speedup vs baseline: 2.7082x; 1.0831x over previous
//
#include <hip/hip_runtime.h>
#include <math.h>

#define FL 48
#define NBLK 512
#define NTHR 256
#define TTOT (NBLK * NTHR)

struct Params {
  const float* ximg;
  const int *e0, *e1, *e2, *e3;
  const float *g1Wl, *g1bl, *g1Wr;
  const float *gWl[3], *gbl[3], *gWr[3];
  const float *amW[3], *amb[3], *axW[3], *axb[3];
  const float *cWl[3], *cbl[3], *cWr[3];
  const float *fc1W, *fc1b, *fc2W, *fc2b;
  float* out;
  unsigned* bar;
  float *xp1, *xp2, *xp3, *x4;
  float *cnt0, *cnt1, *cnt2, *cnt3;
  float *aggS0, *aggS1, *aggS2, *aggS3;
  float *aggC2, *aggC3, *aggC4;
  float *sum1, *max1, *sum2, *max2, *sum3, *max3;
  float *dl2, *dr2, *dl3, *dr3, *dl4, *dr4;
  float *fc1acc;
};

__device__ __forceinline__ float sigmoidf(float v) { return 1.0f / (1.0f + expf(-v)); }

// device-coherent (cross-XCD) load/store of workspace data; no fences needed.
__device__ __forceinline__ float gld(const float* p) {
  return __hip_atomic_load(p, __ATOMIC_RELAXED, __HIP_MEMORY_SCOPE_AGENT);
}
__device__ __forceinline__ void gst(float* p, float v) {
  __hip_atomic_store(p, v, __ATOMIC_RELAXED, __HIP_MEMORY_SCOPE_AGENT);
}

// Grid barrier: monotonic arrival counter, no reset, no fences.
// __syncthreads() drains each wave's vmem (compiler emits vmcnt(0) before
// s_barrier), so all of this block's coherent stores are visible before arrival.
__device__ __forceinline__ void gbar(unsigned* bar, unsigned& gen) {
  gen += NBLK;
  __syncthreads();
  if (threadIdx.x == 0) {
    __hip_atomic_fetch_add(bar, 1u, __ATOMIC_RELAXED, __HIP_MEMORY_SCOPE_AGENT);
    while (__hip_atomic_load(bar, __ATOMIC_RELAXED, __HIP_MEMORY_SCOPE_AGENT) < gen)
      __builtin_amdgcn_s_sleep(1);
  }
  __syncthreads();
}

// att[t] = sigmoid(mean@amW + amb + max@axW + axb), redundant per block into LDS
__device__ void compute_att_lds(const float* sum, const float* mxv, float invN,
                                const float* amW, const float* amb,
                                const float* axW, const float* axb, float* sAtt) {
  int t = threadIdx.x;
  if (t < FL) {
    float s = amb[t] + axb[t];
    for (int ci = 0; ci < FL; ++ci)
      s += (gld(&sum[ci]) * invN) * amW[ci * FL + t] + gld(&mxv[ci]) * axW[ci * FL + t];
    sAtt[t] = sigmoidf(s);
  }
}

template <int POOL, int HAS_NEXT>
__device__ void do_level(const Params& p, int gid, unsigned& gen,
                         const float* x, int N, int H, const int* e, int E,
                         const float* cnt, const float* dl, const float* dr,
                         const float* amW, const float* amb,
                         const float* axW, const float* axb,
                         const float* cblv, const float* sum, const float* mxv,
                         const float* Wl, const float* bl, const float* Wr,
                         float* aggS, float* aggC, float* y, int Nout,
                         float* nsum, float* nmax, float* ndl, float* ndr,
                         const float* ncWl, const float* ncWr,
                         float* sWl, float* sWr, float* sAtt,
                         float* lsum, unsigned* lmax) {
  // Phase A: edge-only scatter aggS[d] += dl[s]; att vector into LDS
  for (int i = gid; i < E; i += TTOT)
    atomicAdd(&aggS[e[E + i]], gld(&dl[e[i]]));
  compute_att_lds(sum, mxv, 1.0f / (float)N, amW, amb, axW, axb, sAtt);
  gbar(p.bar, gen);

  float cb = cblv[0];
  // Phase C: gated edge scatter aggC[d][c] += x[s][c]*(1+att[c]+ch[s]); stage weights
  for (int g = gid; g < E * FL; g += TTOT) {
    int ei = g / FL, c = g % FL;
    int s = e[ei], d = e[E + ei];
    float ch = sigmoidf(gld(&aggS[s]) / fmaxf(gld(&cnt[s]), 1.0f) + cb + gld(&dr[s]));
    atomicAdd(&aggC[d * FL + c], gld(&x[s * FL + c]) * (1.0f + sAtt[c] + ch));
  }
  for (int i = threadIdx.x; i < FL * FL; i += NTHR) { sWl[i] = Wl[i]; sWr[i] = Wr[i]; }
  gbar(p.bar, gen);

  // Phase D: gated SAGE (+pool); fused next-level stats + next-level dl/dr dots
  if (HAS_NEXT && threadIdx.x < FL) { lsum[threadIdx.x] = 0.0f; lmax[threadIdx.x] = 0u; }
  __syncthreads();
  for (int g = gid; g < Nout * FL; g += TTOT) {
    int c = g % FL, m = g / FL;
    float result;
    if (POOL) {
      int Ho = H >> 1;
      int a = m / Ho, b = m % Ho;
      float best = -INFINITY;
#pragma unroll
      for (int da = 0; da < 2; ++da)
#pragma unroll
        for (int db = 0; db < 2; ++db) {
          int n = (2 * a + da) * H + (2 * b + db);
          float rc = 1.0f / fmaxf(gld(&cnt[n]), 1.0f);
          float ch = sigmoidf(gld(&aggS[n]) * rc + cb + gld(&dr[n]));
          const float* xr = x + n * FL;
          const float* ar = aggC + n * FL;
          float s = bl[c];
          for (int ci = 0; ci < FL; ++ci)
            s += gld(&ar[ci]) * rc * sWl[ci * FL + c] +
                 gld(&xr[ci]) * (1.0f + sAtt[ci] + ch) * sWr[ci * FL + c];
          best = fmaxf(best, fmaxf(s, 0.0f));
        }
      result = best;
    } else {
      int n = m;
      float rc = 1.0f / fmaxf(gld(&cnt[n]), 1.0f);
      float ch = sigmoidf(gld(&aggS[n]) * rc + cb + gld(&dr[n]));
      const float* xr = x + n * FL;
      const float* ar = aggC + n * FL;
      float s = bl[c];
      for (int ci = 0; ci < FL; ++ci)
        s += gld(&ar[ci]) * rc * sWl[ci * FL + c] +
             gld(&xr[ci]) * (1.0f + sAtt[ci] + ch) * sWr[ci * FL + c];
      result = fmaxf(s, 0.0f);
    }
    gst(&y[g], result);
    if (HAS_NEXT) {
      atomicAdd(&lsum[c], result);
      atomicMax(&lmax[c], __float_as_uint(result));  // post-relu >= 0
      atomicAdd(&ndl[m], result * ncWl[c]);
      atomicAdd(&ndr[m], result * ncWr[c]);
    }
  }
  __syncthreads();
  if (HAS_NEXT && threadIdx.x < FL) {
    atomicAdd(&nsum[threadIdx.x], lsum[threadIdx.x]);
    atomicMax((unsigned*)&nmax[threadIdx.x], lmax[threadIdx.x]);
  }
  gbar(p.bar, gen);
}

__global__ __launch_bounds__(NTHR) void net_kernel(Params p) {
  const int gid = blockIdx.x * NTHR + threadIdx.x;
  unsigned gen = 0;
  __shared__ float sWl[FL * FL], sWr[FL * FL], sAtt[FL];
  __shared__ float lsum[FL];
  __shared__ unsigned lmax[FL];

  // P1: degree counts x4 + level-1 scalar scatter (zeroing done by memset node)
  for (int g = gid; g < 87040; g += TTOT) {
    if (g < 65536) {
      int d = p.e0[65536 + g];
      atomicAdd(&p.cnt0[d], 1.0f);
      atomicAdd(&p.aggS0[d], p.ximg[p.e0[g]]);
    } else if (g < 81920) {
      atomicAdd(&p.cnt1[p.e1[16384 + (g - 65536)]], 1.0f);
    } else if (g < 86016) {
      atomicAdd(&p.cnt2[p.e2[4096 + (g - 81920)]], 1.0f);
    } else {
      atomicAdd(&p.cnt3[p.e3[1024 + (g - 86016)]], 1.0f);
    }
  }
  gbar(p.bar, gen);

  // P2: sage1 (C_in=1) + relu + pool 128->64, fused att1 stats + dl2/dr2 dots
  if (threadIdx.x < FL) { lsum[threadIdx.x] = 0.0f; lmax[threadIdx.x] = 0u; }
  __syncthreads();
  for (int g = gid; g < 4096 * FL; g += TTOT) {
    int c = g % FL, m = g / FL;
    int a = m >> 6, b = m & 63;
    float wl = p.g1Wl[c], wr = p.g1Wr[c], bb = p.g1bl[c];
    float best = -INFINITY;
#pragma unroll
    for (int da = 0; da < 2; ++da)
#pragma unroll
      for (int db = 0; db < 2; ++db) {
        int n = (2 * a + da) * 128 + (2 * b + db);
        float mean = gld(&p.aggS0[n]) / fmaxf(gld(&p.cnt0[n]), 1.0f);
        best = fmaxf(best, fmaxf(mean * wl + bb + p.ximg[n] * wr, 0.0f));
      }
    gst(&p.xp1[g], best);
    atomicAdd(&lsum[c], best);
    atomicMax(&lmax[c], __float_as_uint(best));
    atomicAdd(&p.dl2[m], best * p.cWl[0][c]);
    atomicAdd(&p.dr2[m], best * p.cWr[0][c]);
  }
  __syncthreads();
  if (threadIdx.x < FL) {
    atomicAdd(&p.sum1[threadIdx.x], lsum[threadIdx.x]);
    atomicMax((unsigned*)&p.max1[threadIdx.x], lmax[threadIdx.x]);
  }
  gbar(p.bar, gen);

  // levels 2..4
  do_level<1, 1>(p, gid, gen, p.xp1, 4096, 64, p.e1, 16384, p.cnt1, p.dl2, p.dr2,
                 p.amW[0], p.amb[0], p.axW[0], p.axb[0], p.cbl[0], p.sum1, p.max1,
                 p.gWl[0], p.gbl[0], p.gWr[0],
                 p.aggS1, p.aggC2, p.xp2, 1024,
                 p.sum2, p.max2, p.dl3, p.dr3, p.cWl[1], p.cWr[1],
                 sWl, sWr, sAtt, lsum, lmax);
  do_level<1, 1>(p, gid, gen, p.xp2, 1024, 32, p.e2, 4096, p.cnt2, p.dl3, p.dr3,
                 p.amW[1], p.amb[1], p.axW[1], p.axb[1], p.cbl[1], p.sum2, p.max2,
                 p.gWl[1], p.gbl[1], p.gWr[1],
                 p.aggS2, p.aggC3, p.xp3, 256,
                 p.sum3, p.max3, p.dl4, p.dr4, p.cWl[2], p.cWr[2],
                 sWl, sWr, sAtt, lsum, lmax);
  do_level<0, 0>(p, gid, gen, p.xp3, 256, 16, p.e3, 1024, p.cnt3, p.dl4, p.dr4,
                 p.amW[2], p.amb[2], p.axW[2], p.axb[2], p.cbl[2], p.sum3, p.max3,
                 p.gWl[2], p.gbl[2], p.gWr[2],
                 p.aggS3, p.aggC4, p.x4, 256,
                 (float*)nullptr, (float*)nullptr, (float*)nullptr, (float*)nullptr,
                 (const float*)nullptr, (const float*)nullptr,
                 sWl, sWr, sAtt, lsum, lmax);

  // FC1 on blocks 0..127: block b covers k in [b*96, b*96+96); k = c*256+n -> x4[n*48+c]
  if (blockIdx.x < 128) {
    __shared__ float xin[96];
    int k0 = blockIdx.x * 96;
    int t = threadIdx.x;
    if (t < 96) {
      int k = k0 + t;
      xin[t] = gld(&p.x4[(k & 255) * FL + (k >> 8)]);
    }
    __syncthreads();
    float a = 0.0f;
    for (int i = 0; i < 96; ++i) a += xin[i] * p.fc1W[(size_t)(k0 + i) * 256 + t];
    atomicAdd(&p.fc1acc[t], a);
  }
  gbar(p.bar, gen);

  // final: fc1 bias+relu, fc2, log_softmax (block 0)
  if (blockIdx.x == 0) {
    __shared__ float av[256];
    __shared__ float logits[10];
    int t = threadIdx.x;
    av[t] = fmaxf(gld(&p.fc1acc[t]) + p.fc1b[t], 0.0f);
    __syncthreads();
    if (t < 10) {
      float s = p.fc2b[t];
      for (int o = 0; o < 256; ++o) s += av[o] * p.fc2W[o * 10 + t];
      logits[t] = s;
    }
    __syncthreads();
    if (t == 0) {
      float m = logits[0];
      for (int j = 1; j < 10; ++j) m = fmaxf(m, logits[j]);
      float s = 0.0f;
      for (int j = 0; j < 10; ++j) s += expf(logits[j] - m);
      float ls = logf(s);
      for (int j = 0; j < 10; ++j) p.out[j] = logits[j] - m - ls;
    }
  }
}

// ---------------- launch ----------------

extern "C" void kernel_launch(void* const* d_in, const int* in_sizes, int n_in,
                              void* d_out, int out_size, void* d_ws, size_t ws_size,
                              hipStream_t stream) {
  Params p;
  p.ximg = (const float*)d_in[0];
  p.e0 = (const int*)d_in[1];
  p.e1 = (const int*)d_in[2];
  p.e2 = (const int*)d_in[3];
  p.e3 = (const int*)d_in[4];
  p.g1Wl = (const float*)d_in[6];
  p.g1bl = (const float*)d_in[7];
  p.g1Wr = (const float*)d_in[8];
  for (int i = 0; i < 3; ++i) {
    p.gWl[i] = (const float*)d_in[9 + i * 3];
    p.gbl[i] = (const float*)d_in[10 + i * 3];
    p.gWr[i] = (const float*)d_in[11 + i * 3];
    int base = 18 + i * 7;
    p.amW[i] = (const float*)d_in[base + 0];
    p.amb[i] = (const float*)d_in[base + 1];
    p.axW[i] = (const float*)d_in[base + 2];
    p.axb[i] = (const float*)d_in[base + 3];
    p.cWl[i] = (const float*)d_in[base + 4];
    p.cbl[i] = (const float*)d_in[base + 5];
    p.cWr[i] = (const float*)d_in[base + 6];
  }
  p.fc1W = (const float*)d_in[46];
  p.fc1b = (const float*)d_in[47];
  p.fc2W = (const float*)d_in[48];
  p.fc2b = (const float*)d_in[49];
  p.out = (float*)d_out;

  const int N0 = 16384, N1 = 4096, N2 = 1024, N3 = 256;
  // layout: [bar: 32 u32][zero region][non-zeroed xp buffers]
  p.bar = (unsigned*)d_ws;
  float* f = (float*)d_ws + 32;
  float* zbase = f;
  p.cnt0 = f;    f += N0;
  p.cnt1 = f;    f += N1;
  p.cnt2 = f;    f += N2;
  p.cnt3 = f;    f += N3;
  p.aggS0 = f;   f += N0;
  p.aggS1 = f;   f += N1;
  p.aggS2 = f;   f += N2;
  p.aggS3 = f;   f += N3;
  p.aggC2 = f;   f += N1 * FL;
  p.aggC3 = f;   f += N2 * FL;
  p.aggC4 = f;   f += N3 * FL;
  p.sum1 = f;    f += FL;
  p.max1 = f;    f += FL;
  p.sum2 = f;    f += FL;
  p.max2 = f;    f += FL;
  p.sum3 = f;    f += FL;
  p.max3 = f;    f += FL;
  p.dl2 = f;     f += N1;
  p.dr2 = f;     f += N1;
  p.dl3 = f;     f += N2;
  p.dr3 = f;     f += N2;
  p.dl4 = f;     f += N3;
  p.dr4 = f;     f += N3;
  p.fc1acc = f;  f += 256;
  size_t zbytes = (size_t)((char*)f - (char*)d_ws);
  p.xp1 = f;     f += N1 * FL;
  p.xp2 = f;     f += N2 * FL;
  p.xp3 = f;     f += N3 * FL;
  p.x4 = f;      f += N3 * FL;

  // one memset node zeroes barrier + all accumulators
  hipMemsetAsync(d_ws, 0, zbytes, stream);

  void* args[] = {&p};
  hipLaunchCooperativeKernel((const void*)net_kernel, dim3(NBLK), dim3(NTHR), args, 0, stream);

  (void)in_sizes; (void)n_in; (void)out_size; (void)ws_size; (void)zbase;
}

// Round 6
// 340.590 us; speedup vs baseline: 2.7770x; 1.0254x over previous
//
#include <hip/hip_runtime.h>
#include <math.h>

#define FL 48
#define NBLK 512
#define NTHR 256
#define TTOT (NBLK * NTHR)

struct Params {
  const float* ximg;
  const int *e0, *e1, *e2, *e3;
  const float *g1Wl, *g1bl, *g1Wr;
  const float *gWl[3], *gbl[3], *gWr[3];
  const float *amW[3], *amb[3], *axW[3], *axb[3];
  const float *cWl[3], *cbl[3], *cWr[3];
  const float *fc1W, *fc1b, *fc2W, *fc2b;
  float* out;
  unsigned* bar;
  float *xp1, *xp2, *xp3, *x4;
  float *cnt0, *cnt1, *cnt2, *cnt3;
  float *aggS0, *aggS1, *aggS2, *aggS3;
  float *aggC2, *aggC3, *aggC4;
  float *sum1, *max1, *sum2, *max2, *sum3, *max3;
  float *dl2, *dr2, *dl3, *dr3, *dl4, *dr4;
  float *fc1acc;
};

__device__ __forceinline__ float sigmoidf(float v) { return 1.0f / (1.0f + expf(-v)); }

// Producer-side store: write-through to the device coherence point so readers
// on other XCDs (whose L2 never cached the line) fetch the fresh value.
__device__ __forceinline__ void gst(float* p, float v) {
  __hip_atomic_store(p, v, __ATOMIC_RELAXED, __HIP_MEMORY_SCOPE_AGENT);
}

// Grid barrier: monotonic arrival counter, no cache maintenance.
// __syncthreads() drains vmem (vmcnt(0)) so this block's coherent writes are
// done before arrival; signal fences stop the compiler moving loads across.
__device__ __forceinline__ void gbar(unsigned* bar, unsigned& gen) {
  gen += NBLK;
  __atomic_signal_fence(__ATOMIC_ACQ_REL);
  __syncthreads();
  if (threadIdx.x == 0) {
    __hip_atomic_fetch_add(bar, 1u, __ATOMIC_RELAXED, __HIP_MEMORY_SCOPE_AGENT);
    while (__hip_atomic_load(bar, __ATOMIC_RELAXED, __HIP_MEMORY_SCOPE_AGENT) < gen)
      __builtin_amdgcn_s_sleep(1);
  }
  __syncthreads();
  __atomic_signal_fence(__ATOMIC_ACQ_REL);
}

// att[t] = sigmoid(mean@amW + amb + max@axW + axb), redundant per block into LDS
__device__ void compute_att_lds(const float* sum, const float* mxv, float invN,
                                const float* amW, const float* amb,
                                const float* axW, const float* axb, float* sAtt) {
  int t = threadIdx.x;
  if (t < FL) {
    float s = amb[t] + axb[t];
    for (int ci = 0; ci < FL; ++ci)
      s += (sum[ci] * invN) * amW[ci * FL + t] + mxv[ci] * axW[ci * FL + t];
    sAtt[t] = sigmoidf(s);
  }
}

template <int POOL, int HAS_NEXT>
__device__ void do_level(const Params& p, int gid, unsigned& gen,
                         const float* x, int N, int H, const int* e, int E,
                         const float* cnt, const float* dl, const float* dr,
                         const float* amW, const float* amb,
                         const float* axW, const float* axb,
                         const float* cblv, const float* sum, const float* mxv,
                         const float* Wl, const float* bl, const float* Wr,
                         float* aggS, float* aggC, float* y, int Nout,
                         float* nsum, float* nmax, float* ndl, float* ndr,
                         const float* ncWl, const float* ncWr,
                         float* sWl, float* sWr, float* sAtt,
                         float* lsum, unsigned* lmax) {
  // Phase A: edge-only scatter aggS[d] += dl[s]; att vector into LDS
  for (int i = gid; i < E; i += TTOT)
    atomicAdd(&aggS[e[E + i]], dl[e[i]]);
  compute_att_lds(sum, mxv, 1.0f / (float)N, amW, amb, axW, axb, sAtt);
  gbar(p.bar, gen);

  float cb = cblv[0];
  // Phase C: gated edge scatter aggC[d][c] += x[s][c]*(1+att[c]+ch[s]); stage weights
  for (int g = gid; g < E * FL; g += TTOT) {
    int ei = g / FL, c = g % FL;
    int s = e[ei], d = e[E + ei];
    float ch = sigmoidf(aggS[s] / fmaxf(cnt[s], 1.0f) + cb + dr[s]);
    atomicAdd(&aggC[d * FL + c], x[s * FL + c] * (1.0f + sAtt[c] + ch));
  }
  for (int i = threadIdx.x; i < FL * FL; i += NTHR) { sWl[i] = Wl[i]; sWr[i] = Wr[i]; }
  gbar(p.bar, gen);

  // Phase D: gated SAGE (+pool); fused next-level stats + next-level dl/dr dots
  if (HAS_NEXT && threadIdx.x < FL) { lsum[threadIdx.x] = 0.0f; lmax[threadIdx.x] = 0u; }
  __syncthreads();
  for (int g = gid; g < Nout * FL; g += TTOT) {
    int c = g % FL, m = g / FL;
    float result;
    if (POOL) {
      int Ho = H >> 1;
      int a = m / Ho, b = m % Ho;
      float best = -INFINITY;
#pragma unroll
      for (int da = 0; da < 2; ++da)
#pragma unroll
        for (int db = 0; db < 2; ++db) {
          int n = (2 * a + da) * H + (2 * b + db);
          float rc = 1.0f / fmaxf(cnt[n], 1.0f);
          float ch = sigmoidf(aggS[n] * rc + cb + dr[n]);
          const float* xr = x + n * FL;
          const float* ar = aggC + n * FL;
          float s = bl[c];
          for (int ci = 0; ci < FL; ++ci)
            s += ar[ci] * rc * sWl[ci * FL + c] +
                 xr[ci] * (1.0f + sAtt[ci] + ch) * sWr[ci * FL + c];
          best = fmaxf(best, fmaxf(s, 0.0f));
        }
      result = best;
    } else {
      int n = m;
      float rc = 1.0f / fmaxf(cnt[n], 1.0f);
      float ch = sigmoidf(aggS[n] * rc + cb + dr[n]);
      const float* xr = x + n * FL;
      const float* ar = aggC + n * FL;
      float s = bl[c];
      for (int ci = 0; ci < FL; ++ci)
        s += ar[ci] * rc * sWl[ci * FL + c] +
             xr[ci] * (1.0f + sAtt[ci] + ch) * sWr[ci * FL + c];
      result = fmaxf(s, 0.0f);
    }
    gst(&y[g], result);
    if (HAS_NEXT) {
      atomicAdd(&lsum[c], result);
      atomicMax(&lmax[c], __float_as_uint(result));  // post-relu >= 0
      atomicAdd(&ndl[m], result * ncWl[c]);
      atomicAdd(&ndr[m], result * ncWr[c]);
    }
  }
  __syncthreads();
  if (HAS_NEXT && threadIdx.x < FL) {
    atomicAdd(&nsum[threadIdx.x], lsum[threadIdx.x]);
    atomicMax((unsigned*)&nmax[threadIdx.x], lmax[threadIdx.x]);
  }
  gbar(p.bar, gen);
}

__global__ __launch_bounds__(NTHR) void net_kernel(Params p) {
  const int gid = blockIdx.x * NTHR + threadIdx.x;
  unsigned gen = 0;
  __shared__ float sWl[FL * FL], sWr[FL * FL], sAtt[FL];
  __shared__ float lsum[FL];
  __shared__ unsigned lmax[FL];

  // P1: degree counts x4 + level-1 scalar scatter (zeroing done by memset node)
  for (int g = gid; g < 87040; g += TTOT) {
    if (g < 65536) {
      int d = p.e0[65536 + g];
      atomicAdd(&p.cnt0[d], 1.0f);
      atomicAdd(&p.aggS0[d], p.ximg[p.e0[g]]);
    } else if (g < 81920) {
      atomicAdd(&p.cnt1[p.e1[16384 + (g - 65536)]], 1.0f);
    } else if (g < 86016) {
      atomicAdd(&p.cnt2[p.e2[4096 + (g - 81920)]], 1.0f);
    } else {
      atomicAdd(&p.cnt3[p.e3[1024 + (g - 86016)]], 1.0f);
    }
  }
  gbar(p.bar, gen);

  // P2: sage1 (C_in=1) + relu + pool 128->64, fused att1 stats + dl2/dr2 dots
  if (threadIdx.x < FL) { lsum[threadIdx.x] = 0.0f; lmax[threadIdx.x] = 0u; }
  __syncthreads();
  for (int g = gid; g < 4096 * FL; g += TTOT) {
    int c = g % FL, m = g / FL;
    int a = m >> 6, b = m & 63;
    float wl = p.g1Wl[c], wr = p.g1Wr[c], bb = p.g1bl[c];
    float best = -INFINITY;
#pragma unroll
    for (int da = 0; da < 2; ++da)
#pragma unroll
      for (int db = 0; db < 2; ++db) {
        int n = (2 * a + da) * 128 + (2 * b + db);
        float mean = p.aggS0[n] / fmaxf(p.cnt0[n], 1.0f);
        best = fmaxf(best, fmaxf(mean * wl + bb + p.ximg[n] * wr, 0.0f));
      }
    gst(&p.xp1[g], best);
    atomicAdd(&lsum[c], best);
    atomicMax(&lmax[c], __float_as_uint(best));
    atomicAdd(&p.dl2[m], best * p.cWl[0][c]);
    atomicAdd(&p.dr2[m], best * p.cWr[0][c]);
  }
  __syncthreads();
  if (threadIdx.x < FL) {
    atomicAdd(&p.sum1[threadIdx.x], lsum[threadIdx.x]);
    atomicMax((unsigned*)&p.max1[threadIdx.x], lmax[threadIdx.x]);
  }
  gbar(p.bar, gen);

  // levels 2..4
  do_level<1, 1>(p, gid, gen, p.xp1, 4096, 64, p.e1, 16384, p.cnt1, p.dl2, p.dr2,
                 p.amW[0], p.amb[0], p.axW[0], p.axb[0], p.cbl[0], p.sum1, p.max1,
                 p.gWl[0], p.gbl[0], p.gWr[0],
                 p.aggS1, p.aggC2, p.xp2, 1024,
                 p.sum2, p.max2, p.dl3, p.dr3, p.cWl[1], p.cWr[1],
                 sWl, sWr, sAtt, lsum, lmax);
  do_level<1, 1>(p, gid, gen, p.xp2, 1024, 32, p.e2, 4096, p.cnt2, p.dl3, p.dr3,
                 p.amW[1], p.amb[1], p.axW[1], p.axb[1], p.cbl[1], p.sum2, p.max2,
                 p.gWl[1], p.gbl[1], p.gWr[1],
                 p.aggS2, p.aggC3, p.xp3, 256,
                 p.sum3, p.max3, p.dl4, p.dr4, p.cWl[2], p.cWr[2],
                 sWl, sWr, sAtt, lsum, lmax);
  do_level<0, 0>(p, gid, gen, p.xp3, 256, 16, p.e3, 1024, p.cnt3, p.dl4, p.dr4,
                 p.amW[2], p.amb[2], p.axW[2], p.axb[2], p.cbl[2], p.sum3, p.max3,
                 p.gWl[2], p.gbl[2], p.gWr[2],
                 p.aggS3, p.aggC4, p.x4, 256,
                 (float*)nullptr, (float*)nullptr, (float*)nullptr, (float*)nullptr,
                 (const float*)nullptr, (const float*)nullptr,
                 sWl, sWr, sAtt, lsum, lmax);

  // FC1 on blocks 0..127: block b covers k in [b*96, b*96+96); k = c*256+n -> x4[n*48+c]
  if (blockIdx.x < 128) {
    __shared__ float xin[96];
    int k0 = blockIdx.x * 96;
    int t = threadIdx.x;
    if (t < 96) {
      int k = k0 + t;
      xin[t] = p.x4[(k & 255) * FL + (k >> 8)];
    }
    __syncthreads();
    float a = 0.0f;
    for (int i = 0; i < 96; ++i) a += xin[i] * p.fc1W[(size_t)(k0 + i) * 256 + t];
    atomicAdd(&p.fc1acc[t], a);
  }
  gbar(p.bar, gen);

  // final: fc1 bias+relu, fc2, log_softmax (block 0)
  if (blockIdx.x == 0) {
    __shared__ float av[256];
    __shared__ float logits[10];
    int t = threadIdx.x;
    av[t] = fmaxf(p.fc1acc[t] + p.fc1b[t], 0.0f);
    __syncthreads();
    if (t < 10) {
      float s = p.fc2b[t];
      for (int o = 0; o < 256; ++o) s += av[o] * p.fc2W[o * 10 + t];
      logits[t] = s;
    }
    __syncthreads();
    if (t == 0) {
      float m = logits[0];
      for (int j = 1; j < 10; ++j) m = fmaxf(m, logits[j]);
      float s = 0.0f;
      for (int j = 0; j < 10; ++j) s += expf(logits[j] - m);
      float ls = logf(s);
      for (int j = 0; j < 10; ++j) p.out[j] = logits[j] - m - ls;
    }
  }
}

// ---------------- launch ----------------

extern "C" void kernel_launch(void* const* d_in, const int* in_sizes, int n_in,
                              void* d_out, int out_size, void* d_ws, size_t ws_size,
                              hipStream_t stream) {
  Params p;
  p.ximg = (const float*)d_in[0];
  p.e0 = (const int*)d_in[1];
  p.e1 = (const int*)d_in[2];
  p.e2 = (const int*)d_in[3];
  p.e3 = (const int*)d_in[4];
  p.g1Wl = (const float*)d_in[6];
  p.g1bl = (const float*)d_in[7];
  p.g1Wr = (const float*)d_in[8];
  for (int i = 0; i < 3; ++i) {
    p.gWl[i] = (const float*)d_in[9 + i * 3];
    p.gbl[i] = (const float*)d_in[10 + i * 3];
    p.gWr[i] = (const float*)d_in[11 + i * 3];
    int base = 18 + i * 7;
    p.amW[i] = (const float*)d_in[base + 0];
    p.amb[i] = (const float*)d_in[base + 1];
    p.axW[i] = (const float*)d_in[base + 2];
    p.axb[i] = (const float*)d_in[base + 3];
    p.cWl[i] = (const float*)d_in[base + 4];
    p.cbl[i] = (const float*)d_in[base + 5];
    p.cWr[i] = (const float*)d_in[base + 6];
  }
  p.fc1W = (const float*)d_in[46];
  p.fc1b = (const float*)d_in[47];
  p.fc2W = (const float*)d_in[48];
  p.fc2b = (const float*)d_in[49];
  p.out = (float*)d_out;

  const int N0 = 16384, N1 = 4096, N2 = 1024, N3 = 256;
  // Every buffer padded to a 4 KB (1024-float) boundary: no cache line spans
  // two buffers, so first-touch-after-producer-barrier is line-exact.
  float* base = (float*)d_ws;
  size_t off = 1024;  // first 4 KB: barrier state
  auto alloc = [&](size_t n) -> float* {
    float* q = base + off;
    off += (n + 1023) & ~(size_t)1023;
    return q;
  };
  p.bar = (unsigned*)d_ws;
  p.cnt0 = alloc(N0);
  p.cnt1 = alloc(N1);
  p.cnt2 = alloc(N2);
  p.cnt3 = alloc(N3);
  p.aggS0 = alloc(N0);
  p.aggS1 = alloc(N1);
  p.aggS2 = alloc(N2);
  p.aggS3 = alloc(N3);
  p.aggC2 = alloc(N1 * FL);
  p.aggC3 = alloc(N2 * FL);
  p.aggC4 = alloc(N3 * FL);
  p.sum1 = alloc(FL);
  p.max1 = alloc(FL);
  p.sum2 = alloc(FL);
  p.max2 = alloc(FL);
  p.sum3 = alloc(FL);
  p.max3 = alloc(FL);
  p.dl2 = alloc(N1);
  p.dr2 = alloc(N1);
  p.dl3 = alloc(N2);
  p.dr3 = alloc(N2);
  p.dl4 = alloc(N3);
  p.dr4 = alloc(N3);
  p.fc1acc = alloc(256);
  size_t zbytes = off * sizeof(float);  // barrier + all accumulators
  p.xp1 = alloc(N1 * FL);
  p.xp2 = alloc(N2 * FL);
  p.xp3 = alloc(N3 * FL);
  p.x4 = alloc(N3 * FL);

  // one memset node zeroes barrier + all accumulators
  hipMemsetAsync(d_ws, 0, zbytes, stream);

  void* args[] = {&p};
  hipLaunchCooperativeKernel((const void*)net_kernel, dim3(NBLK), dim3(NTHR), args, 0, stream);

  (void)in_sizes; (void)n_in; (void)out_size; (void)ws_size;
}

// Round 7
// 190.832 us; speedup vs baseline: 4.9562x; 1.7848x over previous
//
#include <hip/hip_runtime.h>
#include <math.h>

#define FL 48

__device__ __forceinline__ float sigmoidf(float v) { return 1.0f / (1.0f + expf(-v)); }

// att[t] = sigmoid(mean@amW + amb + max@axW + axb) into LDS (redundant per block;
// amW/axW are L2-hot). Caller must __syncthreads() before using sAtt.
__device__ __forceinline__ void att_lds(const float* sum, const float* mxv, float invN,
                                        const float* amW, const float* amb,
                                        const float* axW, const float* axb, float* sAtt) {
  int t = threadIdx.x;
  if (t < FL) {
    float s = amb[t] + axb[t];
    for (int ci = 0; ci < FL; ++ci)
      s += (sum[ci] * invN) * amW[ci * FL + t] + mxv[ci] * axW[ci * FL + t];
    sAtt[t] = sigmoidf(s);
  }
}

// ---------------- kernels ----------------

// degree counts for all 4 edge lists + level-1 scalar scatter (C_in=1)
__global__ __launch_bounds__(256) void k_prep(
    const int* __restrict__ e0, const int* __restrict__ e1,
    const int* __restrict__ e2, const int* __restrict__ e3,
    const float* __restrict__ ximg,
    float* __restrict__ cnt0, float* __restrict__ cnt1,
    float* __restrict__ cnt2, float* __restrict__ cnt3,
    float* __restrict__ aggS0) {
  int g = blockIdx.x * 256 + threadIdx.x;
  if (g < 65536) {
    int d = e0[65536 + g];
    atomicAdd(&cnt0[d], 1.0f);
    atomicAdd(&aggS0[d], ximg[e0[g]]);
  } else if (g < 81920) {
    atomicAdd(&cnt1[e1[16384 + (g - 65536)]], 1.0f);
  } else if (g < 86016) {
    atomicAdd(&cnt2[e2[4096 + (g - 81920)]], 1.0f);
  } else if (g < 87040) {
    atomicAdd(&cnt3[e3[1024 + (g - 86016)]], 1.0f);
  }
}

// sage1 (C_in=1) + relu + pool 128->64 -> xp1; fused: att1 stats + dl2/dr2 dots
__global__ __launch_bounds__(256) void k_p2(
    const float* __restrict__ x, const float* __restrict__ agg, const float* __restrict__ cnt,
    const float* __restrict__ Wl, const float* __restrict__ bl, const float* __restrict__ Wr,
    const float* __restrict__ cWl, const float* __restrict__ cWr,
    float* __restrict__ y, float* __restrict__ sum1, float* __restrict__ max1,
    float* __restrict__ dl, float* __restrict__ dr) {
  __shared__ float lsum[FL];
  __shared__ unsigned lmax[FL];
  if (threadIdx.x < FL) { lsum[threadIdx.x] = 0.0f; lmax[threadIdx.x] = 0u; }
  __syncthreads();
  int g = blockIdx.x * 256 + threadIdx.x;
  if (g < 4096 * FL) {
    int c = g % FL, m = g / FL;
    int a = m >> 6, b = m & 63;
    float wl = Wl[c], wr = Wr[c], bb = bl[c];
    float best = -INFINITY;
#pragma unroll
    for (int da = 0; da < 2; ++da)
#pragma unroll
      for (int db = 0; db < 2; ++db) {
        int n = (2 * a + da) * 128 + (2 * b + db);
        float mean = agg[n] / fmaxf(cnt[n], 1.0f);
        best = fmaxf(best, fmaxf(mean * wl + bb + x[n] * wr, 0.0f));
      }
    y[g] = best;
    atomicAdd(&lsum[c], best);
    atomicMax(&lmax[c], __float_as_uint(best));  // post-relu >= 0
    atomicAdd(&dl[m], best * cWl[c]);
    atomicAdd(&dr[m], best * cWr[c]);
  }
  __syncthreads();
  if (threadIdx.x < FL) {
    atomicAdd(&sum1[threadIdx.x], lsum[threadIdx.x]);
    atomicMax((unsigned*)&max1[threadIdx.x], lmax[threadIdx.x]);
  }
}

// edge scatter: aggS[dst] += dl[src]
__global__ __launch_bounds__(256) void k_edge(const int* __restrict__ e, int E,
                                              const float* __restrict__ dl,
                                              float* __restrict__ aggS) {
  int i = blockIdx.x * 256 + threadIdx.x;
  if (i < E) atomicAdd(&aggS[e[E + i]], dl[e[i]]);
}

// gated edge scatter: aggC[d][c] += x[s][c]*(1+att[c]+ch[s]); att computed in-block
__global__ __launch_bounds__(256) void k_gscat(
    const int* __restrict__ e, int E, int N,
    const float* __restrict__ x,
    const float* __restrict__ sum, const float* __restrict__ mxv,
    const float* __restrict__ amW, const float* __restrict__ amb,
    const float* __restrict__ axW, const float* __restrict__ axb,
    const float* __restrict__ aggS, const float* __restrict__ cnt,
    const float* __restrict__ dr, const float* __restrict__ cbl,
    float* __restrict__ aggC) {
  __shared__ float sAtt[FL];
  att_lds(sum, mxv, 1.0f / (float)N, amW, amb, axW, axb, sAtt);
  __syncthreads();
  int g = blockIdx.x * 256 + threadIdx.x;
  if (g >= E * FL) return;
  int ei = g / FL, c = g % FL;
  int s = e[ei], d = e[E + ei];
  float ch = sigmoidf(aggS[s] / fmaxf(cnt[s], 1.0f) + cbl[0] + dr[s]);
  atomicAdd(&aggC[d * FL + c], x[s * FL + c] * (1.0f + sAtt[c] + ch));
}

// gated SAGE (+pool); att in-block; fused next-level stats + dl/dr dots
template <int POOL, int HAS_NEXT>
__global__ __launch_bounds__(256) void k_gsage(
    const float* __restrict__ x, int N, int H, int Nout,
    const float* __restrict__ sum, const float* __restrict__ mxv,
    const float* __restrict__ amW, const float* __restrict__ amb,
    const float* __restrict__ axW, const float* __restrict__ axb,
    const float* __restrict__ aggS, const float* __restrict__ cnt,
    const float* __restrict__ dr, const float* __restrict__ cbl,
    const float* __restrict__ aggC,
    const float* __restrict__ Wl, const float* __restrict__ bl,
    const float* __restrict__ Wr,
    float* __restrict__ y,
    float* __restrict__ nsum, float* __restrict__ nmax,
    float* __restrict__ ndl, float* __restrict__ ndr,
    const float* __restrict__ ncWl, const float* __restrict__ ncWr) {
  __shared__ float sWl[FL * FL], sWr[FL * FL], sAtt[FL];
  __shared__ float lsum[FL];
  __shared__ unsigned lmax[FL];
  att_lds(sum, mxv, 1.0f / (float)N, amW, amb, axW, axb, sAtt);
  for (int i = threadIdx.x; i < FL * FL; i += 256) { sWl[i] = Wl[i]; sWr[i] = Wr[i]; }
  if (HAS_NEXT && threadIdx.x < FL) { lsum[threadIdx.x] = 0.0f; lmax[threadIdx.x] = 0u; }
  __syncthreads();
  int g = blockIdx.x * 256 + threadIdx.x;
  float cb = cbl[0];
  if (g < Nout * FL) {
    int c = g % FL, m = g / FL;
    float result;
    if (POOL) {
      int Ho = H >> 1;
      int a = m / Ho, b = m % Ho;
      float best = -INFINITY;
#pragma unroll
      for (int da = 0; da < 2; ++da)
#pragma unroll
        for (int db = 0; db < 2; ++db) {
          int n = (2 * a + da) * H + (2 * b + db);
          float rc = 1.0f / fmaxf(cnt[n], 1.0f);
          float ch = sigmoidf(aggS[n] * rc + cb + dr[n]);
          const float* xr = x + n * FL;
          const float* ar = aggC + n * FL;
          float s = bl[c];
          for (int ci = 0; ci < FL; ++ci)
            s += ar[ci] * rc * sWl[ci * FL + c] +
                 xr[ci] * (1.0f + sAtt[ci] + ch) * sWr[ci * FL + c];
          best = fmaxf(best, fmaxf(s, 0.0f));
        }
      result = best;
    } else {
      int n = m;
      float rc = 1.0f / fmaxf(cnt[n], 1.0f);
      float ch = sigmoidf(aggS[n] * rc + cb + dr[n]);
      const float* xr = x + n * FL;
      const float* ar = aggC + n * FL;
      float s = bl[c];
      for (int ci = 0; ci < FL; ++ci)
        s += ar[ci] * rc * sWl[ci * FL + c] +
             xr[ci] * (1.0f + sAtt[ci] + ch) * sWr[ci * FL + c];
      result = fmaxf(s, 0.0f);
    }
    y[g] = result;
    if (HAS_NEXT) {
      atomicAdd(&lsum[c], result);
      atomicMax(&lmax[c], __float_as_uint(result));
      atomicAdd(&ndl[m], result * ncWl[c]);
      atomicAdd(&ndr[m], result * ncWr[c]);
    }
  }
  __syncthreads();
  if (HAS_NEXT && threadIdx.x < FL) {
    atomicAdd(&nsum[threadIdx.x], lsum[threadIdx.x]);
    atomicMax((unsigned*)&nmax[threadIdx.x], lmax[threadIdx.x]);
  }
}

// FC1 split-K: block b covers k in [b*96, b*96+96); k = c*256+n -> x4[n*48+c]
__global__ __launch_bounds__(256) void k_fc1(const float* __restrict__ x4,
                                             const float* __restrict__ W,
                                             float* __restrict__ acc) {
  __shared__ float xin[96];
  int k0 = blockIdx.x * 96;
  int t = threadIdx.x;
  if (t < 96) {
    int k = k0 + t;
    xin[t] = x4[(k & 255) * FL + (k >> 8)];
  }
  __syncthreads();
  float a = 0.0f;
  for (int i = 0; i < 96; ++i) a += xin[i] * W[(size_t)(k0 + i) * 256 + t];
  atomicAdd(&acc[t], a);
}

// fc1 bias+relu, fc2, log_softmax
__global__ void k_final(const float* __restrict__ acc, const float* __restrict__ b1,
                        const float* __restrict__ W2, const float* __restrict__ b2,
                        float* __restrict__ out) {
  __shared__ float av[256];
  __shared__ float logits[10];
  int t = threadIdx.x;
  av[t] = fmaxf(acc[t] + b1[t], 0.0f);
  __syncthreads();
  if (t < 10) {
    float s = b2[t];
    for (int o = 0; o < 256; ++o) s += av[o] * W2[o * 10 + t];
    logits[t] = s;
  }
  __syncthreads();
  if (t == 0) {
    float m = logits[0];
    for (int j = 1; j < 10; ++j) m = fmaxf(m, logits[j]);
    float s = 0.0f;
    for (int j = 0; j < 10; ++j) s += expf(logits[j] - m);
    float ls = logf(s);
    for (int j = 0; j < 10; ++j) out[j] = logits[j] - m - ls;
  }
}

// ---------------- launch ----------------

static inline int cdiv(int a, int b) { return (a + b - 1) / b; }

extern "C" void kernel_launch(void* const* d_in, const int* in_sizes, int n_in,
                              void* d_out, int out_size, void* d_ws, size_t ws_size,
                              hipStream_t stream) {
  const float* ximg = (const float*)d_in[0];
  const int* e1v = (const int*)d_in[2];
  const int* e2v = (const int*)d_in[3];
  const int* e3v = (const int*)d_in[4];
  const float* g1Wl = (const float*)d_in[6];
  const float* g1bl = (const float*)d_in[7];
  const float* g1Wr = (const float*)d_in[8];
  const float* gWl[3] = {(const float*)d_in[9], (const float*)d_in[12], (const float*)d_in[15]};
  const float* gbl[3] = {(const float*)d_in[10], (const float*)d_in[13], (const float*)d_in[16]};
  const float* gWr[3] = {(const float*)d_in[11], (const float*)d_in[14], (const float*)d_in[17]};
  const float* amW[3]; const float* amb[3]; const float* axW[3]; const float* axb[3];
  const float* cWl[3]; const float* cbl[3]; const float* cWr[3];
  for (int i = 0; i < 3; ++i) {
    int base = 18 + i * 7;
    amW[i] = (const float*)d_in[base + 0];
    amb[i] = (const float*)d_in[base + 1];
    axW[i] = (const float*)d_in[base + 2];
    axb[i] = (const float*)d_in[base + 3];
    cWl[i] = (const float*)d_in[base + 4];
    cbl[i] = (const float*)d_in[base + 5];
    cWr[i] = (const float*)d_in[base + 6];
  }
  const float* fc1W = (const float*)d_in[46];
  const float* fc1b = (const float*)d_in[47];
  const float* fc2W = (const float*)d_in[48];
  const float* fc2b = (const float*)d_in[49];
  float* out = (float*)d_out;

  const int N0 = 16384, N1 = 4096, N2 = 1024, N3 = 256;
  const int E0 = 65536, E1 = 16384, E2 = 4096, E3 = 1024;

  // 4KB-padded buffers; [zeroed region][non-zeroed feature buffers]
  float* base = (float*)d_ws;
  size_t off = 0;
  auto alloc = [&](size_t n) -> float* {
    float* q = base + off;
    off += (n + 1023) & ~(size_t)1023;
    return q;
  };
  float* cnt0 = alloc(N0);
  float* cnt1 = alloc(N1);
  float* cnt2 = alloc(N2);
  float* cnt3 = alloc(N3);
  float* aggS0 = alloc(N0);
  float* aggS1 = alloc(N1);
  float* aggS2 = alloc(N2);
  float* aggS3 = alloc(N3);
  float* aggC2 = alloc(N1 * FL);
  float* aggC3 = alloc(N2 * FL);
  float* aggC4 = alloc(N3 * FL);
  float* sum1 = alloc(FL); float* max1 = alloc(FL);
  float* sum2 = alloc(FL); float* max2 = alloc(FL);
  float* sum3 = alloc(FL); float* max3 = alloc(FL);
  float* dl2 = alloc(N1); float* dr2 = alloc(N1);
  float* dl3 = alloc(N2); float* dr3 = alloc(N2);
  float* dl4 = alloc(N3); float* dr4 = alloc(N3);
  float* fc1acc = alloc(256);
  size_t zbytes = off * sizeof(float);
  float* xp1 = alloc(N1 * FL);
  float* xp2 = alloc(N2 * FL);
  float* xp3 = alloc(N3 * FL);
  float* x4 = alloc(N3 * FL);

  // 1: zero accumulators (single memset node)
  hipMemsetAsync(d_ws, 0, zbytes, stream);

  // 2: counts + lvl1 scatter
  k_prep<<<cdiv(87040, 256), 256, 0, stream>>>((const int*)d_in[1], e1v, e2v, e3v, ximg,
                                               cnt0, cnt1, cnt2, cnt3, aggS0);
  // 3: sage1+pool -> xp1 (+att1 stats, dl2/dr2)
  k_p2<<<cdiv(N1 * FL, 256), 256, 0, stream>>>(ximg, aggS0, cnt0, g1Wl, g1bl, g1Wr,
                                               cWl[0], cWr[0], xp1, sum1, max1, dl2, dr2);

  // ---- level 2 (graph e1) ----
  k_edge<<<cdiv(E1, 256), 256, 0, stream>>>(e1v, E1, dl2, aggS1);
  k_gscat<<<cdiv(E1 * FL, 256), 256, 0, stream>>>(e1v, E1, N1, xp1, sum1, max1,
                                                  amW[0], amb[0], axW[0], axb[0],
                                                  aggS1, cnt1, dr2, cbl[0], aggC2);
  k_gsage<1, 1><<<cdiv(N2 * FL, 256), 256, 0, stream>>>(
      xp1, N1, 64, N2, sum1, max1, amW[0], amb[0], axW[0], axb[0],
      aggS1, cnt1, dr2, cbl[0], aggC2, gWl[0], gbl[0], gWr[0],
      xp2, sum2, max2, dl3, dr3, cWl[1], cWr[1]);

  // ---- level 3 (graph e2) ----
  k_edge<<<cdiv(E2, 256), 256, 0, stream>>>(e2v, E2, dl3, aggS2);
  k_gscat<<<cdiv(E2 * FL, 256), 256, 0, stream>>>(e2v, E2, N2, xp2, sum2, max2,
                                                  amW[1], amb[1], axW[1], axb[1],
                                                  aggS2, cnt2, dr3, cbl[1], aggC3);
  k_gsage<1, 1><<<cdiv(N3 * FL, 256), 256, 0, stream>>>(
      xp2, N2, 32, N3, sum2, max2, amW[1], amb[1], axW[1], axb[1],
      aggS2, cnt2, dr3, cbl[1], aggC3, gWl[1], gbl[1], gWr[1],
      xp3, sum3, max3, dl4, dr4, cWl[2], cWr[2]);

  // ---- level 4 (graph e3, no pool) ----
  k_edge<<<cdiv(E3, 256), 256, 0, stream>>>(e3v, E3, dl4, aggS3);
  k_gscat<<<cdiv(E3 * FL, 256), 256, 0, stream>>>(e3v, E3, N3, xp3, sum3, max3,
                                                  amW[2], amb[2], axW[2], axb[2],
                                                  aggS3, cnt3, dr4, cbl[2], aggC4);
  k_gsage<0, 0><<<cdiv(N3 * FL, 256), 256, 0, stream>>>(
      xp3, N3, 16, N3, sum3, max3, amW[2], amb[2], axW[2], axb[2],
      aggS3, cnt3, dr4, cbl[2], aggC4, gWl[2], gbl[2], gWr[2],
      x4, (float*)nullptr, (float*)nullptr, (float*)nullptr, (float*)nullptr,
      (const float*)nullptr, (const float*)nullptr);

  // ---- FC head ----
  k_fc1<<<128, 256, 0, stream>>>(x4, fc1W, fc1acc);
  k_final<<<1, 256, 0, stream>>>(fc1acc, fc1b, fc2W, fc2b, out);

  (void)in_sizes; (void)n_in; (void)out_size; (void)ws_size;
}

// Round 8
// 108.654 us; speedup vs baseline: 8.7048x; 1.7563x over previous
//
#include <hip/hip_runtime.h>
#include <math.h>

#define FL 48

__device__ __forceinline__ float sigmoidf(float v) { return 1.0f / (1.0f + expf(-v)); }

// att[t] = sigmoid(mean@amW + amb + max@axW + axb) into LDS (redundant per block).
// Caller must __syncthreads() before using sAtt.
__device__ __forceinline__ void att_lds(const float* sum, const float* mxv, float invN,
                                        const float* amW, const float* amb,
                                        const float* axW, const float* axb, float* sAtt) {
  int t = threadIdx.x;
  if (t < FL) {
    float s = amb[t] + axb[t];
    for (int ci = 0; ci < FL; ++ci)
      s += (sum[ci] * invN) * amW[ci * FL + t] + mxv[ci] * axW[ci * FL + t];
    sAtt[t] = sigmoidf(s);
  }
}

// ---------------- kernels ----------------

// degree counts for all 4 edge lists + level-1 scalar scatter (C_in=1)
__global__ __launch_bounds__(256) void k_prep(
    const int* __restrict__ e0, const int* __restrict__ e1,
    const int* __restrict__ e2, const int* __restrict__ e3,
    const float* __restrict__ ximg,
    float* __restrict__ cnt0, float* __restrict__ cnt1,
    float* __restrict__ cnt2, float* __restrict__ cnt3,
    float* __restrict__ aggS0) {
  int g = blockIdx.x * 256 + threadIdx.x;
  if (g < 65536) {
    int d = e0[65536 + g];
    atomicAdd(&cnt0[d], 1.0f);
    atomicAdd(&aggS0[d], ximg[e0[g]]);
  } else if (g < 81920) {
    atomicAdd(&cnt1[e1[16384 + (g - 65536)]], 1.0f);
  } else if (g < 86016) {
    atomicAdd(&cnt2[e2[4096 + (g - 81920)]], 1.0f);
  } else if (g < 87040) {
    atomicAdd(&cnt3[e3[1024 + (g - 86016)]], 1.0f);
  }
}

// exclusive prefix-sum of the 3 degree arrays (one block each)
__global__ __launch_bounds__(256) void k_scan(
    const float* __restrict__ cnt1, int* __restrict__ off1,
    const float* __restrict__ cnt2, int* __restrict__ off2,
    const float* __restrict__ cnt3, int* __restrict__ off3) {
  const float* cnt; int* off; int N;
  if (blockIdx.x == 0) { cnt = cnt1; off = off1; N = 4096; }
  else if (blockIdx.x == 1) { cnt = cnt2; off = off2; N = 1024; }
  else { cnt = cnt3; off = off3; N = 256; }
  __shared__ int part[256];
  int t = threadIdx.x;
  int chunk = N / 256;  // 16, 4, 1
  int base = t * chunk;
  int s = 0;
  for (int i = 0; i < chunk; ++i) s += (int)cnt[base + i];
  part[t] = s;
  __syncthreads();
  for (int o = 1; o < 256; o <<= 1) {
    int v = (t >= o) ? part[t - o] : 0;
    __syncthreads();
    part[t] += v;
    __syncthreads();
  }
  int run = part[t] - s;  // exclusive prefix of this chunk
  for (int i = 0; i < chunk; ++i) { off[base + i] = run; run += (int)cnt[base + i]; }
  if (t == 255) off[N] = part[255];
}

// CSR fill (all 3 graphs) + sage1(C_in=1)+relu+pool 128->64 -> xp1
__global__ __launch_bounds__(256) void k_fill_s1(
    const int* __restrict__ e1, const int* __restrict__ e2, const int* __restrict__ e3,
    const int* __restrict__ off1, int* __restrict__ cur1, int* __restrict__ csr1,
    const int* __restrict__ off2, int* __restrict__ cur2, int* __restrict__ csr2,
    const int* __restrict__ off3, int* __restrict__ cur3, int* __restrict__ csr3,
    const float* __restrict__ ximg, const float* __restrict__ aggS0,
    const float* __restrict__ cnt0,
    const float* __restrict__ Wl, const float* __restrict__ bl, const float* __restrict__ Wr,
    float* __restrict__ xp1) {
  int blk = blockIdx.x;
  if (blk < 84) {  // 21504 edges total
    int i = blk * 256 + threadIdx.x;
    if (i < 16384) {
      int s = e1[i], d = e1[16384 + i];
      csr1[off1[d] + atomicAdd(&cur1[d], 1)] = s;
    } else if (i < 20480) {
      int ii = i - 16384;
      int s = e2[ii], d = e2[4096 + ii];
      csr2[off2[d] + atomicAdd(&cur2[d], 1)] = s;
    } else if (i < 21504) {
      int ii = i - 20480;
      int s = e3[ii], d = e3[1024 + ii];
      csr3[off3[d] + atomicAdd(&cur3[d], 1)] = s;
    }
  } else {
    int g = (blk - 84) * 256 + threadIdx.x;
    if (g < 4096 * FL) {
      int c = g % FL, m = g / FL;
      int a = m >> 6, b = m & 63;
      float wl = Wl[c], wr = Wr[c], bb = bl[c];
      float best = -INFINITY;
#pragma unroll
      for (int da = 0; da < 2; ++da)
#pragma unroll
        for (int db = 0; db < 2; ++db) {
          int n = (2 * a + da) * 128 + (2 * b + db);
          float mean = aggS0[n] / fmaxf(cnt0[n], 1.0f);
          best = fmaxf(best, fmaxf(mean * wl + bb + ximg[n] * wr, 0.0f));
        }
      xp1[g] = best;
    }
  }
}

// A: per-channel stats (owner blocks 0..47, no atomics) +
//    per-node channel gate ch[n] = sigmoid(mean_gather + cbl + x[n].cWr)  (CSR gather)
__global__ __launch_bounds__(256) void k_A(
    const float* __restrict__ x, int N,
    const int* __restrict__ csr, const int* __restrict__ off,
    const float* __restrict__ cntf,
    const float* __restrict__ cWl, const float* __restrict__ cWr,
    const float* __restrict__ cbl,
    float* __restrict__ sum, float* __restrict__ mxv, float* __restrict__ ch) {
  if (blockIdx.x < FL) {
    int c = blockIdx.x, t = threadIdx.x;
    float s = 0.0f, m = -INFINITY;
    for (int n = t; n < N; n += 256) {
      float v = x[n * FL + c];
      s += v; m = fmaxf(m, v);
    }
    __shared__ float ss[256], sm[256];
    ss[t] = s; sm[t] = m;
    __syncthreads();
    for (int o = 128; o > 0; o >>= 1) {
      if (t < o) { ss[t] += ss[t + o]; sm[t] = fmaxf(sm[t], sm[t + o]); }
      __syncthreads();
    }
    if (t == 0) { sum[c] = ss[0]; mxv[c] = sm[0]; }
  } else {
    int n = (blockIdx.x - FL) * 256 + threadIdx.x;
    if (n >= N) return;
    const float* xr = x + n * FL;
    float dr = 0.0f;
    for (int c = 0; c < FL; ++c) dr += xr[c] * cWr[c];
    float g = 0.0f;
    int j0 = off[n], j1 = off[n + 1];
    for (int j = j0; j < j1; ++j) {
      const float* xs = x + csr[j] * FL;
      float a = 0.0f;
      for (int c = 0; c < FL; ++c) a += xs[c] * cWl[c];
      g += a;
    }
    float mean = g / fmaxf(cntf[n], 1.0f);
    ch[n] = sigmoidf(mean + cbl[0] + dr);
  }
}

// B: gated SAGE via CSR gather (+pool). Block = 4 output nodes (16 or 4 subnodes).
template <int POOL>
__global__ __launch_bounds__(256) void k_B(
    const float* __restrict__ x, int N, int H,
    const int* __restrict__ csr, const int* __restrict__ off,
    const float* __restrict__ cntf, const float* __restrict__ ch,
    const float* __restrict__ sum, const float* __restrict__ mxv,
    const float* __restrict__ amW, const float* __restrict__ amb,
    const float* __restrict__ axW, const float* __restrict__ axb,
    const float* __restrict__ Wl, const float* __restrict__ bl,
    const float* __restrict__ Wr,
    float* __restrict__ y) {
  const int NS = POOL ? 16 : 4;
  __shared__ float sWl[FL * FL], sWr[FL * FL], sAtt[FL];
  __shared__ float smean[16][FL], sx[16][FL];
  int t = threadIdx.x;
  att_lds(sum, mxv, 1.0f / (float)N, amW, amb, axW, axb, sAtt);
  for (int i = t; i < FL * FL; i += 256) { sWl[i] = Wl[i]; sWr[i] = Wr[i]; }
  __syncthreads();
  int Ho = H >> 1;
  // gather phase: (subnode k, channel ci); 48 consecutive lanes read one row -> coalesced
  for (int idx = t; idx < NS * FL; idx += 256) {
    int k = idx / FL, ci = idx % FL;
    int m = blockIdx.x * 4 + (POOL ? (k >> 2) : k);
    int n;
    if (POOL) {
      int a = m / Ho, b = m % Ho;
      n = (2 * a + ((k >> 1) & 1)) * H + (2 * b + (k & 1));
    } else {
      n = m;
    }
    float g1 = 1.0f + sAtt[ci];
    float acc = 0.0f;
    for (int j = off[n]; j < off[n + 1]; ++j) {
      int s = csr[j];
      acc += x[s * FL + ci] * (g1 + ch[s]);
    }
    smean[k][ci] = acc / fmaxf(cntf[n], 1.0f);
    sx[k][ci] = x[n * FL + ci] * (g1 + ch[n]);
  }
  __syncthreads();
  // output phase: (out node q, channel c)
  if (t < 4 * FL) {
    int q = t / FL, c = t % FL;
    int m = blockIdx.x * 4 + q;
    float best = -INFINITY;
#pragma unroll
    for (int sub = 0; sub < (POOL ? 4 : 1); ++sub) {
      int k = POOL ? q * 4 + sub : q;
      float s = bl[c];
      for (int ci = 0; ci < FL; ++ci)
        s += smean[k][ci] * sWl[ci * FL + c] + sx[k][ci] * sWr[ci * FL + c];
      best = fmaxf(best, fmaxf(s, 0.0f));
    }
    y[m * FL + c] = best;
  }
}

// FC1 split-K: block b covers k in [b*96, b*96+96); k = c*256+n -> x4[n*48+c]
__global__ __launch_bounds__(256) void k_fc1(const float* __restrict__ x4,
                                             const float* __restrict__ W,
                                             float* __restrict__ acc) {
  __shared__ float xin[96];
  int k0 = blockIdx.x * 96;
  int t = threadIdx.x;
  if (t < 96) {
    int k = k0 + t;
    xin[t] = x4[(k & 255) * FL + (k >> 8)];
  }
  __syncthreads();
  float a = 0.0f;
  for (int i = 0; i < 96; ++i) a += xin[i] * W[(size_t)(k0 + i) * 256 + t];
  atomicAdd(&acc[t], a);
}

// fc1 bias+relu, fc2, log_softmax
__global__ void k_final(const float* __restrict__ acc, const float* __restrict__ b1,
                        const float* __restrict__ W2, const float* __restrict__ b2,
                        float* __restrict__ out) {
  __shared__ float av[256];
  __shared__ float logits[10];
  int t = threadIdx.x;
  av[t] = fmaxf(acc[t] + b1[t], 0.0f);
  __syncthreads();
  if (t < 10) {
    float s = b2[t];
    for (int o = 0; o < 256; ++o) s += av[o] * W2[o * 10 + t];
    logits[t] = s;
  }
  __syncthreads();
  if (t == 0) {
    float m = logits[0];
    for (int j = 1; j < 10; ++j) m = fmaxf(m, logits[j]);
    float s = 0.0f;
    for (int j = 0; j < 10; ++j) s += expf(logits[j] - m);
    float ls = logf(s);
    for (int j = 0; j < 10; ++j) out[j] = logits[j] - m - ls;
  }
}

// ---------------- launch ----------------

static inline int cdiv(int a, int b) { return (a + b - 1) / b; }

extern "C" void kernel_launch(void* const* d_in, const int* in_sizes, int n_in,
                              void* d_out, int out_size, void* d_ws, size_t ws_size,
                              hipStream_t stream) {
  const float* ximg = (const float*)d_in[0];
  const int* e0 = (const int*)d_in[1];
  const int* e1 = (const int*)d_in[2];
  const int* e2 = (const int*)d_in[3];
  const int* e3 = (const int*)d_in[4];
  const float* g1Wl = (const float*)d_in[6];
  const float* g1bl = (const float*)d_in[7];
  const float* g1Wr = (const float*)d_in[8];
  const float* gWl[3] = {(const float*)d_in[9], (const float*)d_in[12], (const float*)d_in[15]};
  const float* gbl[3] = {(const float*)d_in[10], (const float*)d_in[13], (const float*)d_in[16]};
  const float* gWr[3] = {(const float*)d_in[11], (const float*)d_in[14], (const float*)d_in[17]};
  const float* amW[3]; const float* amb[3]; const float* axW[3]; const float* axb[3];
  const float* cWl[3]; const float* cbl[3]; const float* cWr[3];
  for (int i = 0; i < 3; ++i) {
    int base = 18 + i * 7;
    amW[i] = (const float*)d_in[base + 0];
    amb[i] = (const float*)d_in[base + 1];
    axW[i] = (const float*)d_in[base + 2];
    axb[i] = (const float*)d_in[base + 3];
    cWl[i] = (const float*)d_in[base + 4];
    cbl[i] = (const float*)d_in[base + 5];
    cWr[i] = (const float*)d_in[base + 6];
  }
  const float* fc1W = (const float*)d_in[46];
  const float* fc1b = (const float*)d_in[47];
  const float* fc2W = (const float*)d_in[48];
  const float* fc2b = (const float*)d_in[49];
  float* out = (float*)d_out;

  const int N0 = 16384, N1 = 4096, N2 = 1024, N3 = 256;
  const int E1 = 16384, E2 = 4096, E3 = 1024;

  // byte allocator, 4KB-aligned buffers; [zeroed region][rest]
  char* basep = (char*)d_ws;
  size_t off = 0;
  auto alloc = [&](size_t bytes) -> void* {
    void* q = basep + off;
    off += (bytes + 4095) & ~(size_t)4095;
    return q;
  };
  float* cnt0 = (float*)alloc(N0 * 4);
  float* cnt1 = (float*)alloc(N1 * 4);
  float* cnt2 = (float*)alloc(N2 * 4);
  float* cnt3 = (float*)alloc(N3 * 4);
  float* aggS0 = (float*)alloc(N0 * 4);
  int* cur1 = (int*)alloc(N1 * 4);
  int* cur2 = (int*)alloc(N2 * 4);
  int* cur3 = (int*)alloc(N3 * 4);
  float* fc1acc = (float*)alloc(256 * 4);
  size_t zbytes = off;  // everything above must start zeroed
  int* off1 = (int*)alloc((N1 + 1) * 4);
  int* off2 = (int*)alloc((N2 + 1) * 4);
  int* off3 = (int*)alloc((N3 + 1) * 4);
  int* csr1 = (int*)alloc(E1 * 4);
  int* csr2 = (int*)alloc(E2 * 4);
  int* csr3 = (int*)alloc(E3 * 4);
  float* sum1 = (float*)alloc(FL * 4); float* max1 = (float*)alloc(FL * 4);
  float* sum2 = (float*)alloc(FL * 4); float* max2 = (float*)alloc(FL * 4);
  float* sum3 = (float*)alloc(FL * 4); float* max3 = (float*)alloc(FL * 4);
  float* ch2 = (float*)alloc(N1 * 4);
  float* ch3 = (float*)alloc(N2 * 4);
  float* ch4 = (float*)alloc(N3 * 4);
  float* xp1 = (float*)alloc(N1 * FL * 4);
  float* xp2 = (float*)alloc(N2 * FL * 4);
  float* xp3 = (float*)alloc(N3 * FL * 4);
  float* x4 = (float*)alloc(N3 * FL * 4);

  // 1: zero accumulators + cursors
  hipMemsetAsync(d_ws, 0, zbytes, stream);
  // 2: degree counts + lvl1 scalar scatter
  k_prep<<<cdiv(87040, 256), 256, 0, stream>>>(e0, e1, e2, e3, ximg,
                                               cnt0, cnt1, cnt2, cnt3, aggS0);
  // 3: CSR offsets
  k_scan<<<3, 256, 0, stream>>>(cnt1, off1, cnt2, off2, cnt3, off3);
  // 4: CSR fill + sage1pool -> xp1
  k_fill_s1<<<84 + cdiv(N1 * FL, 256), 256, 0, stream>>>(
      e1, e2, e3, off1, cur1, csr1, off2, cur2, csr2, off3, cur3, csr3,
      ximg, aggS0, cnt0, g1Wl, g1bl, g1Wr, xp1);

  // ---- level 2 (graph e1) ----
  k_A<<<FL + cdiv(N1, 256), 256, 0, stream>>>(xp1, N1, csr1, off1, cnt1,
                                              cWl[0], cWr[0], cbl[0], sum1, max1, ch2);
  k_B<1><<<N2 / 4, 256, 0, stream>>>(xp1, N1, 64, csr1, off1, cnt1, ch2, sum1, max1,
                                     amW[0], amb[0], axW[0], axb[0],
                                     gWl[0], gbl[0], gWr[0], xp2);
  // ---- level 3 (graph e2) ----
  k_A<<<FL + cdiv(N2, 256), 256, 0, stream>>>(xp2, N2, csr2, off2, cnt2,
                                              cWl[1], cWr[1], cbl[1], sum2, max2, ch3);
  k_B<1><<<N3 / 4, 256, 0, stream>>>(xp2, N2, 32, csr2, off2, cnt2, ch3, sum2, max2,
                                     amW[1], amb[1], axW[1], axb[1],
                                     gWl[1], gbl[1], gWr[1], xp3);
  // ---- level 4 (graph e3, no pool) ----
  k_A<<<FL + cdiv(N3, 256), 256, 0, stream>>>(xp3, N3, csr3, off3, cnt3,
                                              cWl[2], cWr[2], cbl[2], sum3, max3, ch4);
  k_B<0><<<N3 / 4, 256, 0, stream>>>(xp3, N3, 16, csr3, off3, cnt3, ch4, sum3, max3,
                                     amW[2], amb[2], axW[2], axb[2],
                                     gWl[2], gbl[2], gWr[2], x4);

  // ---- FC head ----
  k_fc1<<<128, 256, 0, stream>>>(x4, fc1W, fc1acc);
  k_final<<<1, 256, 0, stream>>>(fc1acc, fc1b, fc2W, fc2b, out);

  (void)in_sizes; (void)n_in; (void)out_size; (void)ws_size;
}